// Round 1
// baseline (3654.062 us; speedup 1.0000x reference)
//
#include <hip/hip_runtime.h>
#include <math.h>

#define NLAYERS 3
#define NH 8
#define HD 64
#define DST 64
#define DCONV 4
#define DIN 512
#define Bsz 8
#define SEQ 2048
#define Din 128
#define Emb 256
#define DIP 1160
#define CDIM 640
#define M_ROWS (Bsz*SEQ)

__device__ __forceinline__ float sigmoidf_(float x){ return 1.f/(1.f+expf(-x)); }
__device__ __forceinline__ float siluf_(float x){ return x*sigmoidf_(x); }

__global__ void k_softmax_w(const float* __restrict__ w_avg, float* __restrict__ w){
    if(threadIdx.x==0){
        float mx=-1e30f;
        for(int i=0;i<15;i++) mx=fmaxf(mx,w_avg[i]);
        float s=0.f,e[15];
        for(int i=0;i<15;i++){ e[i]=expf(w_avg[i]-mx); s+=e[i]; }
        for(int i=0;i<15;i++) w[i]=e[i]/s;
    }
}

__global__ void k_featsum(const float* __restrict__ feat, const float* __restrict__ w,
                          float* __restrict__ xin){
    int i = blockIdx.x*256+threadIdx.x;     // total M_ROWS*128
    if(i < M_ROWS*Din){
        float acc=0.f;
        #pragma unroll
        for(int n=0;n<15;n++) acc += feat[(size_t)n*M_ROWS*Din + i]*w[n];
        xin[i]=acc;
    }
}

__global__ void k_layernorm(const float* __restrict__ in, const float* __restrict__ g,
                            const float* __restrict__ b, float* __restrict__ out, int D){
    __shared__ float buf[512];
    __shared__ float red[256];
    int m = blockIdx.x, tid = threadIdx.x;
    float s=0.f;
    for(int i=tid;i<D;i+=256){ float v=in[(size_t)m*D+i]; buf[i]=v; s+=v; }
    red[tid]=s; __syncthreads();
    for(int o=128;o>0;o>>=1){ if(tid<o) red[tid]+=red[tid+o]; __syncthreads(); }
    float mean = red[0]/(float)D; __syncthreads();
    float s2=0.f;
    for(int i=tid;i<D;i+=256){ float d=buf[i]-mean; s2+=d*d; }
    red[tid]=s2; __syncthreads();
    for(int o=128;o>0;o>>=1){ if(tid<o) red[tid]+=red[tid+o]; __syncthreads(); }
    float rstd = rsqrtf(red[0]/(float)D + 1e-5f);
    for(int i=tid;i<D;i+=256) out[(size_t)m*D+i] = (buf[i]-mean)*rstd*g[i]+b[i];
}

__global__ void k_rmsnorm(const float* __restrict__ in, const float* __restrict__ w,
                          float* __restrict__ out, int D){
    __shared__ float red[256];
    int m=blockIdx.x, tid=threadIdx.x;
    float s=0.f;
    for(int i=tid;i<D;i+=256){ float v=in[(size_t)m*D+i]; s+=v*v; }
    red[tid]=s; __syncthreads();
    for(int o=128;o>0;o>>=1){ if(tid<o) red[tid]+=red[tid+o]; __syncthreads(); }
    float rstd=rsqrtf(red[0]/(float)D+1e-5f);
    for(int i=tid;i<D;i+=256) out[(size_t)m*D+i]=in[(size_t)m*D+i]*rstd*w[i];
}

// C[M,N] = A[M,K] @ B[K,N] (+bias)(+act)(+=C). BM=BN=64, BK=16, 256 thr, 4x4 micro.
__global__ void k_gemm(const float* __restrict__ A, const float* __restrict__ Bw,
                       const float* __restrict__ bias, float* __restrict__ C,
                       int M, int N, int K, int accum, int act){
    __shared__ float As[64][17];
    __shared__ float Bs[16][64];
    int n0 = blockIdx.x*64, m0 = blockIdx.y*64;
    int tid = threadIdx.x; int tx = tid & 15, ty = tid >> 4;
    float acc[4][4] = {{0}};
    for(int k0=0;k0<K;k0+=16){
        #pragma unroll
        for(int i=0;i<4;i++){
            int idx=tid+i*256; int ml=idx>>4, kk=idx&15;
            As[ml][kk] = A[(size_t)(m0+ml)*K + k0+kk];
        }
        #pragma unroll
        for(int i=0;i<4;i++){
            int idx=tid+i*256; int kk=idx>>6, nl=idx&63;
            int n=n0+nl;
            Bs[kk][nl] = (n<N)? Bw[(size_t)(k0+kk)*N + n] : 0.f;
        }
        __syncthreads();
        #pragma unroll
        for(int kk=0;kk<16;kk++){
            float a0=As[ty*4+0][kk], a1=As[ty*4+1][kk], a2=As[ty*4+2][kk], a3=As[ty*4+3][kk];
            float b0=Bs[kk][tx*4+0], b1=Bs[kk][tx*4+1], b2=Bs[kk][tx*4+2], b3=Bs[kk][tx*4+3];
            acc[0][0]+=a0*b0; acc[0][1]+=a0*b1; acc[0][2]+=a0*b2; acc[0][3]+=a0*b3;
            acc[1][0]+=a1*b0; acc[1][1]+=a1*b1; acc[1][2]+=a1*b2; acc[1][3]+=a1*b3;
            acc[2][0]+=a2*b0; acc[2][1]+=a2*b1; acc[2][2]+=a2*b2; acc[2][3]+=a2*b3;
            acc[3][0]+=a3*b0; acc[3][1]+=a3*b1; acc[3][2]+=a3*b2; acc[3][3]+=a3*b3;
        }
        __syncthreads();
    }
    #pragma unroll
    for(int i=0;i<4;i++){
        #pragma unroll
        for(int j=0;j<4;j++){
            int m=m0+ty*4+i, n=n0+tx*4+j;
            if(n<N){
                float v=acc[i][j];
                if(bias) v+=bias[n];
                if(act==1) v = 0.5f*v*(1.f+erff(v*0.70710678118f));
                size_t o=(size_t)m*N+n;
                if(accum) C[o]+=v; else C[o]=v;
            }
        }
    }
}

__global__ void k_dt(const float* __restrict__ zx, const float* __restrict__ dtbias,
                     const float* __restrict__ Alog, float* __restrict__ dt, float* __restrict__ da){
    int i = blockIdx.x*256+threadIdx.x;     // M_ROWS*NH
    if(i<M_ROWS*NH){
        int m=i>>3, h=i&7;
        float v = zx[(size_t)m*DIP + (DIP-NH) + h] + dtbias[h];
        float d = (v>20.f)? v : log1pf(expf(v));
        dt[i]=d;
        da[i]=expf(-expf(Alog[h])*d);
    }
}

__global__ void k_conv(const float* __restrict__ zx, const float* __restrict__ cw,
                       const float* __restrict__ cb, float* __restrict__ xc){
    int i = blockIdx.x*256+threadIdx.x;     // M_ROWS*CDIM
    if(i >= M_ROWS*CDIM) return;
    int c = i % CDIM; int m = i / CDIM; int s = m % SEQ;
    float acc = cb[c];
    #pragma unroll
    for(int k=0;k<4;k++){
        int t = s+k-3;
        if(t>=0) acc += zx[(size_t)(m+(t-s))*DIP + DIN + c] * cw[c*4+k];
    }
    xc[i] = siluf_(acc);
}

// one block per (b, head, p-chunk of 16). 256 thr: pl=tid>>4 (p local), nq=tid&15 (4 n each)
__global__ void __launch_bounds__(256) k_scan(const float* __restrict__ xc, const float* __restrict__ dt,
                      const float* __restrict__ da, const float* __restrict__ Dp, float* __restrict__ y){
    int blk = blockIdx.x;
    int pcidx = blk & 3;
    int h = (blk>>2) & 7;
    int b = blk>>5;
    int tid = threadIdx.x;
    int pl = tid >> 4;
    int p = pcidx*16 + pl;
    int nq = tid & 15;
    const float* xcb = xc + (size_t)b*SEQ*CDIM;
    const float* dtp = dt + (size_t)b*SEQ*NH + h;
    const float* dap = da + (size_t)b*SEQ*NH + h;
    float* yb = y + (size_t)b*SEQ*DIN + h*HD + p;
    float Dv = Dp[h];
    float hr[4] = {0.f,0.f,0.f,0.f};
    int xoff = h*HD + p;
    int boff = DIN + nq*4;
    int coff = DIN + DST + nq*4;
    float xv = xcb[xoff];
    float4 Bv = *(const float4*)(xcb + boff);
    float4 Cv = *(const float4*)(xcb + coff);
    float dtv = dtp[0], dav = dap[0];
    for(int t=0;t<SEQ;t++){
        float nxv=0.f, ndt=0.f, nda=0.f; float4 nB=make_float4(0,0,0,0), nC=make_float4(0,0,0,0);
        if(t+1<SEQ){
            const float* nx = xcb + (size_t)(t+1)*CDIM;
            nxv = nx[xoff];
            nB = *(const float4*)(nx+boff);
            nC = *(const float4*)(nx+coff);
            ndt = dtp[(size_t)(t+1)*NH];
            nda = dap[(size_t)(t+1)*NH];
        }
        float coef = dtv*xv;
        hr[0]=hr[0]*dav+coef*Bv.x; hr[1]=hr[1]*dav+coef*Bv.y;
        hr[2]=hr[2]*dav+coef*Bv.z; hr[3]=hr[3]*dav+coef*Bv.w;
        float part = hr[0]*Cv.x + hr[1]*Cv.y + hr[2]*Cv.z + hr[3]*Cv.w;
        part += __shfl_xor(part,1,16);
        part += __shfl_xor(part,2,16);
        part += __shfl_xor(part,4,16);
        part += __shfl_xor(part,8,16);
        if(nq==0) yb[(size_t)t*DIN] = part + xv*Dv;
        xv=nxv; Bv=nB; Cv=nC; dtv=ndt; dav=nda;
    }
}

__global__ void k_gatenorm(const float* __restrict__ zx, const float* __restrict__ gnw,
                           float* __restrict__ y){
    __shared__ float red[256];
    int m = blockIdx.x, tid = threadIdx.x;
    size_t yb = (size_t)m*DIN, zb = (size_t)m*DIP;
    float g0 = y[yb+tid]     * siluf_(zx[zb+tid]);
    float g1 = y[yb+256+tid] * siluf_(zx[zb+256+tid]);
    red[tid] = g0*g0+g1*g1; __syncthreads();
    for(int o=128;o>0;o>>=1){ if(tid<o) red[tid]+=red[tid+o]; __syncthreads(); }
    float rstd = rsqrtf(red[0]*(1.f/512.f)+1e-5f);
    y[yb+tid]     = g0*rstd*gnw[tid];
    y[yb+256+tid] = g1*rstd*gnw[256+tid];
}

__global__ void k_mlp2(const float* __restrict__ h, const float* __restrict__ W2,
                       const float* __restrict__ b2, float* __restrict__ out){
    __shared__ float red[256];
    int m=blockIdx.x, tid=threadIdx.x;
    float hv=h[(size_t)m*Emb+tid];
    for(int j=0;j<5;j++){
        red[tid]=hv*W2[tid*5+j];
        __syncthreads();
        for(int o=128;o>0;o>>=1){ if(tid<o) red[tid]+=red[tid+o]; __syncthreads(); }
        if(tid==0) out[(size_t)m*5+j]=red[0]+b2[j];
        __syncthreads();
    }
}

extern "C" void kernel_launch(void* const* d_in, const int* in_sizes, int n_in,
                              void* d_out, int out_size, void* d_ws, size_t ws_size,
                              hipStream_t stream){
    const float* feature  = (const float*)d_in[0];
    const float* w_avg    = (const float*)d_in[1];
    const float* ipg      = (const float*)d_in[2];
    const float* ipb      = (const float*)d_in[3];
    const float* ipW      = (const float*)d_in[4];
    const float* ipbias   = (const float*)d_in[5];
    const float* rms_w    = (const float*)d_in[6];
    const float* m_inW    = (const float*)d_in[7];
    const float* m_convW  = (const float*)d_in[8];
    const float* m_convB  = (const float*)d_in[9];
    const float* m_dtb    = (const float*)d_in[10];
    const float* m_Alog   = (const float*)d_in[11];
    const float* m_D      = (const float*)d_in[12];
    const float* m_gnw    = (const float*)d_in[13];
    const float* m_outW   = (const float*)d_in[14];
    const float* norm_w   = (const float*)d_in[15];
    const float* mlp_ln_g = (const float*)d_in[16];
    const float* mlp_ln_b = (const float*)d_in[17];
    const float* W1       = (const float*)d_in[18];
    const float* b1       = (const float*)d_in[19];
    const float* W2       = (const float*)d_in[20];
    const float* b2       = (const float*)d_in[21];
    float* out = (float*)d_out;

    float* ws = (float*)d_ws;
    float* wsoft = ws;                                   // 16
    float* xin   = ws + 16;                              // M*128
    float* xbuf  = xin  + (size_t)M_ROWS*Din;            // M*256
    float* ubuf  = xbuf + (size_t)M_ROWS*Emb;            // M*256
    float* zx    = ubuf + (size_t)M_ROWS*Emb;            // M*1160
    float* xc    = zx   + (size_t)M_ROWS*DIP;            // M*640
    float* dtb2  = xc   + (size_t)M_ROWS*CDIM;           // M*8
    float* dab   = dtb2 + (size_t)M_ROWS*NH;             // M*8
    float* ybuf  = dab  + (size_t)M_ROWS*NH;             // M*512

    k_softmax_w<<<1,64,0,stream>>>(w_avg, wsoft);
    k_featsum<<<(M_ROWS*Din)/256,256,0,stream>>>(feature, wsoft, xin);
    k_layernorm<<<M_ROWS,256,0,stream>>>(xin, ipg, ipb, xin, Din);
    k_gemm<<<dim3(Emb/64, M_ROWS/64),256,0,stream>>>(xin, ipW, ipbias, xbuf, M_ROWS, Emb, Din, 0, 0);

    for(int i=0;i<NLAYERS;i++){
        k_rmsnorm<<<M_ROWS,256,0,stream>>>(xbuf, rms_w + i*Emb, ubuf, Emb);
        k_gemm<<<dim3((DIP+63)/64, M_ROWS/64),256,0,stream>>>(ubuf, m_inW + (size_t)i*Emb*DIP, nullptr, zx, M_ROWS, DIP, Emb, 0, 0);
        k_dt<<<(M_ROWS*NH)/256,256,0,stream>>>(zx, m_dtb + i*NH, m_Alog + i*NH, dtb2, dab);
        k_conv<<<(M_ROWS*CDIM)/256,256,0,stream>>>(zx, m_convW + (size_t)i*CDIM*DCONV, m_convB + i*CDIM, xc);
        k_scan<<<Bsz*NH*4,256,0,stream>>>(xc, dtb2, dab, m_D + i*NH, ybuf);
        k_gatenorm<<<M_ROWS,256,0,stream>>>(zx, m_gnw + i*DIN, ybuf);
        k_gemm<<<dim3(Emb/64, M_ROWS/64),256,0,stream>>>(ybuf, m_outW + (size_t)i*DIN*Emb, nullptr, xbuf, M_ROWS, Emb, DIN, 1, 0);
    }

    k_rmsnorm<<<M_ROWS,256,0,stream>>>(xbuf, norm_w, ubuf, Emb);
    k_layernorm<<<M_ROWS,256,0,stream>>>(ubuf, mlp_ln_g, mlp_ln_b, zx, Emb);
    k_gemm<<<dim3(Emb/64, M_ROWS/64),256,0,stream>>>(zx, W1, b1, ubuf, M_ROWS, Emb, Emb, 0, 1);
    k_mlp2<<<M_ROWS,256,0,stream>>>(ubuf, W2, b2, out);
}

// Round 3
// 2263.336 us; speedup vs baseline: 1.6145x; 1.6145x over previous
//
#include <hip/hip_runtime.h>
#include <math.h>

#define NLAYERS 3
#define NH 8
#define HD 64
#define DST 64
#define DCONV 4
#define DIN 512
#define Bsz 8
#define SEQ 2048
#define Din 128
#define Emb 256
#define DIP 1160
#define CDIM 640
#define M_ROWS (Bsz*SEQ)
#define NCHUNK 8
#define LCH (SEQ/NCHUNK)

__device__ __forceinline__ float sigmoidf_(float x){ return 1.f/(1.f+expf(-x)); }
__device__ __forceinline__ float siluf_(float x){ return x*sigmoidf_(x); }

__global__ void k_softmax_w(const float* __restrict__ w_avg, float* __restrict__ w){
    if(threadIdx.x==0){
        float mx=-1e30f;
        for(int i=0;i<15;i++) mx=fmaxf(mx,w_avg[i]);
        float s=0.f,e[15];
        for(int i=0;i<15;i++){ e[i]=expf(w_avg[i]-mx); s+=e[i]; }
        for(int i=0;i<15;i++) w[i]=e[i]/s;
    }
}

__global__ void k_featsum(const float* __restrict__ feat, const float* __restrict__ w,
                          float* __restrict__ xin){
    int i = blockIdx.x*256+threadIdx.x;
    if(i < M_ROWS*Din){
        float acc=0.f;
        #pragma unroll
        for(int n=0;n<15;n++) acc += feat[(size_t)n*M_ROWS*Din + i]*w[n];
        xin[i]=acc;
    }
}

__global__ void k_layernorm(const float* __restrict__ in, const float* __restrict__ g,
                            const float* __restrict__ b, float* __restrict__ out, int D){
    __shared__ float buf[512];
    __shared__ float red[256];
    int m = blockIdx.x, tid = threadIdx.x;
    float s=0.f;
    for(int i=tid;i<D;i+=256){ float v=in[(size_t)m*D+i]; buf[i]=v; s+=v; }
    red[tid]=s; __syncthreads();
    for(int o=128;o>0;o>>=1){ if(tid<o) red[tid]+=red[tid+o]; __syncthreads(); }
    float mean = red[0]/(float)D; __syncthreads();
    float s2=0.f;
    for(int i=tid;i<D;i+=256){ float d=buf[i]-mean; s2+=d*d; }
    red[tid]=s2; __syncthreads();
    for(int o=128;o>0;o>>=1){ if(tid<o) red[tid]+=red[tid+o]; __syncthreads(); }
    float rstd = rsqrtf(red[0]/(float)D + 1e-5f);
    for(int i=tid;i<D;i+=256) out[(size_t)m*D+i] = (buf[i]-mean)*rstd*g[i]+b[i];
}

__global__ void k_rmsnorm(const float* __restrict__ in, const float* __restrict__ w,
                          float* __restrict__ out, int D){
    __shared__ float red[256];
    int m=blockIdx.x, tid=threadIdx.x;
    float s=0.f;
    for(int i=tid;i<D;i+=256){ float v=in[(size_t)m*D+i]; s+=v*v; }
    red[tid]=s; __syncthreads();
    for(int o=128;o>0;o>>=1){ if(tid<o) red[tid]+=red[tid+o]; __syncthreads(); }
    float rstd=rsqrtf(red[0]/(float)D+1e-5f);
    for(int i=tid;i<D;i+=256) out[(size_t)m*D+i]=in[(size_t)m*D+i]*rstd*w[i];
}

__global__ void k_gemm(const float* __restrict__ A, const float* __restrict__ Bw,
                       const float* __restrict__ bias, float* __restrict__ C,
                       int M, int N, int K, int accum, int act){
    __shared__ float As[64][17];
    __shared__ float Bs[16][64];
    int n0 = blockIdx.x*64, m0 = blockIdx.y*64;
    int tid = threadIdx.x; int tx = tid & 15, ty = tid >> 4;
    float acc[4][4] = {{0}};
    for(int k0=0;k0<K;k0+=16){
        #pragma unroll
        for(int i=0;i<4;i++){
            int idx=tid+i*256; int ml=idx>>4, kk=idx&15;
            As[ml][kk] = A[(size_t)(m0+ml)*K + k0+kk];
        }
        #pragma unroll
        for(int i=0;i<4;i++){
            int idx=tid+i*256; int kk=idx>>6, nl=idx&63;
            int n=n0+nl;
            Bs[kk][nl] = (n<N)? Bw[(size_t)(k0+kk)*N + n] : 0.f;
        }
        __syncthreads();
        #pragma unroll
        for(int kk=0;kk<16;kk++){
            float a0=As[ty*4+0][kk], a1=As[ty*4+1][kk], a2=As[ty*4+2][kk], a3=As[ty*4+3][kk];
            float b0=Bs[kk][tx*4+0], b1=Bs[kk][tx*4+1], b2=Bs[kk][tx*4+2], b3=Bs[kk][tx*4+3];
            acc[0][0]+=a0*b0; acc[0][1]+=a0*b1; acc[0][2]+=a0*b2; acc[0][3]+=a0*b3;
            acc[1][0]+=a1*b0; acc[1][1]+=a1*b1; acc[1][2]+=a1*b2; acc[1][3]+=a1*b3;
            acc[2][0]+=a2*b0; acc[2][1]+=a2*b1; acc[2][2]+=a2*b2; acc[2][3]+=a2*b3;
            acc[3][0]+=a3*b0; acc[3][1]+=a3*b1; acc[3][2]+=a3*b2; acc[3][3]+=a3*b3;
        }
        __syncthreads();
    }
    #pragma unroll
    for(int i=0;i<4;i++){
        #pragma unroll
        for(int j=0;j<4;j++){
            int m=m0+ty*4+i, n=n0+tx*4+j;
            if(n<N){
                float v=acc[i][j];
                if(bias) v+=bias[n];
                if(act==1) v = 0.5f*v*(1.f+erff(v*0.70710678118f));
                size_t o=(size_t)m*N+n;
                if(accum) C[o]+=v; else C[o]=v;
            }
        }
    }
}

__global__ void k_dt(const float* __restrict__ zx, const float* __restrict__ dtbias,
                     const float* __restrict__ Alog, float* __restrict__ dt, float* __restrict__ da){
    int i = blockIdx.x*256+threadIdx.x;
    if(i<M_ROWS*NH){
        int m=i>>3, h=i&7;
        float v = zx[(size_t)m*DIP + (DIP-NH) + h] + dtbias[h];
        float d = (v>20.f)? v : log1pf(expf(v));
        dt[i]=d;
        da[i]=expf(-expf(Alog[h])*d);
    }
}

__global__ void k_conv(const float* __restrict__ zx, const float* __restrict__ cw,
                       const float* __restrict__ cb, float* __restrict__ xc){
    int i = blockIdx.x*256+threadIdx.x;
    if(i >= M_ROWS*CDIM) return;
    int c = i % CDIM; int m = i / CDIM; int s = m % SEQ;
    float acc = cb[c];
    #pragma unroll
    for(int k=0;k<4;k++){
        int t = s+k-3;
        if(t>=0) acc += zx[(size_t)(m+(t-s))*DIP + DIN + c] * cw[c*4+k];
    }
    xc[i] = siluf_(acc);
}

// Pass 1: per-chunk local state S_c (recurrence from 0) and decay product P_c.
__global__ void __launch_bounds__(256) k_scan1(const float* __restrict__ xc, const float* __restrict__ dt,
                       const float* __restrict__ da, float* __restrict__ S, float* __restrict__ P){
    int blk = blockIdx.x;
    int c  = blk & (NCHUNK-1);
    int pc = (blk>>3) & 3;
    int h  = (blk>>5) & 7;
    int b  = blk>>8;
    int tid = threadIdx.x;
    int pl = tid>>4, nq = tid&15;
    int p = pc*16+pl;
    const float* xcb = xc + (size_t)b*SEQ*CDIM;
    const float* dtp = dt + (size_t)b*SEQ*NH + h;
    const float* dap = da + (size_t)b*SEQ*NH + h;
    int xoff = h*HD+p, boff = DIN+nq*4;
    int t0 = c*LCH, t1 = t0+LCH;
    float hr[4]={0,0,0,0};
    float pr = 1.f;
    const float* row = xcb + (size_t)t0*CDIM;
    float xv = row[xoff];
    float4 Bv = *(const float4*)(row+boff);
    float dtv = dtp[(size_t)t0*NH], dav = dap[(size_t)t0*NH];
    for(int t=t0;t<t1;t++){
        float nxv=0.f, ndt=0.f, nda=0.f; float4 nB=make_float4(0,0,0,0);
        if(t+1<t1){
            const float* nr = xcb + (size_t)(t+1)*CDIM;
            nxv = nr[xoff]; nB = *(const float4*)(nr+boff);
            ndt = dtp[(size_t)(t+1)*NH]; nda = dap[(size_t)(t+1)*NH];
        }
        float coef = dtv*xv;
        hr[0]=hr[0]*dav+coef*Bv.x; hr[1]=hr[1]*dav+coef*Bv.y;
        hr[2]=hr[2]*dav+coef*Bv.z; hr[3]=hr[3]*dav+coef*Bv.w;
        pr *= dav;
        xv=nxv; Bv=nB; dtv=ndt; dav=nda;
    }
    size_t sbase = (((size_t)(b*NH+h)*NCHUNK + c)*HD + p)*(size_t)DST + nq*4;
    *(float4*)(S+sbase) = make_float4(hr[0],hr[1],hr[2],hr[3]);
    if(tid==0) P[(b*NH+h)*NCHUNK+c] = pr;
}

// Pass 2: serial combine over the 8 chunks. grid = Bsz*NH*4.
__global__ void __launch_bounds__(256) k_scan2(const float* __restrict__ S, const float* __restrict__ P,
                       float* __restrict__ H){
    int blk = blockIdx.x;
    int pc = blk & 3, h = (blk>>2)&7, b = blk>>5;
    int tid = threadIdx.x;
    int pl = tid>>4, nq = tid&15;
    int p = pc*16+pl;
    size_t base = (((size_t)(b*NH+h)*NCHUNK)*HD + p)*(size_t)DST + nq*4;
    int pb = (b*NH+h)*NCHUNK;
    float4 run = make_float4(0,0,0,0);
    for(int c=0;c<NCHUNK;c++){
        size_t off = base + (size_t)c*HD*DST;
        *(float4*)(H+off) = run;
        float4 s = *(const float4*)(S+off);
        float pp = P[pb+c];
        run.x = run.x*pp + s.x; run.y = run.y*pp + s.y;
        run.z = run.z*pp + s.z; run.w = run.w*pp + s.w;
    }
}

// Pass 3: replay each chunk from H_c, emit y. grid = Bsz*NH*4*NCHUNK.
__global__ void __launch_bounds__(256) k_scan3(const float* __restrict__ xc, const float* __restrict__ dt,
                       const float* __restrict__ da, const float* __restrict__ H,
                       const float* __restrict__ Dp, float* __restrict__ y){
    int blk = blockIdx.x;
    int c  = blk & (NCHUNK-1);
    int pc = (blk>>3) & 3;
    int h  = (blk>>5) & 7;
    int b  = blk>>8;
    int tid = threadIdx.x;
    int pl = tid>>4, nq = tid&15;
    int p = pc*16+pl;
    const float* xcb = xc + (size_t)b*SEQ*CDIM;
    const float* dtp = dt + (size_t)b*SEQ*NH + h;
    const float* dap = da + (size_t)b*SEQ*NH + h;
    float* yb = y + (size_t)b*SEQ*DIN + h*HD + p;
    float Dv = Dp[h];
    int xoff = h*HD+p, boff = DIN+nq*4, coff = DIN+DST+nq*4;
    int t0 = c*LCH, t1 = t0+LCH;
    size_t hbase = (((size_t)(b*NH+h)*NCHUNK + c)*HD + p)*(size_t)DST + nq*4;
    float4 h0 = *(const float4*)(H+hbase);
    float hr[4] = {h0.x,h0.y,h0.z,h0.w};
    const float* row = xcb + (size_t)t0*CDIM;
    float xv = row[xoff];
    float4 Bv = *(const float4*)(row+boff);
    float4 Cv = *(const float4*)(row+coff);
    float dtv = dtp[(size_t)t0*NH], dav = dap[(size_t)t0*NH];
    for(int t=t0;t<t1;t++){
        float nxv=0.f, ndt=0.f, nda=0.f; float4 nB=make_float4(0,0,0,0), nC=make_float4(0,0,0,0);
        if(t+1<t1){
            const float* nr = xcb + (size_t)(t+1)*CDIM;
            nxv = nr[xoff];
            nB = *(const float4*)(nr+boff);
            nC = *(const float4*)(nr+coff);
            ndt = dtp[(size_t)(t+1)*NH];
            nda = dap[(size_t)(t+1)*NH];
        }
        float coef = dtv*xv;
        hr[0]=hr[0]*dav+coef*Bv.x; hr[1]=hr[1]*dav+coef*Bv.y;
        hr[2]=hr[2]*dav+coef*Bv.z; hr[3]=hr[3]*dav+coef*Bv.w;
        float part = hr[0]*Cv.x + hr[1]*Cv.y + hr[2]*Cv.z + hr[3]*Cv.w;
        part += __shfl_xor(part,1,16);
        part += __shfl_xor(part,2,16);
        part += __shfl_xor(part,4,16);
        part += __shfl_xor(part,8,16);
        if(nq==0) yb[(size_t)t*DIN] = part + xv*Dv;
        xv=nxv; Bv=nB; Cv=nC; dtv=ndt; dav=nda;
    }
}

__global__ void k_gatenorm(const float* __restrict__ zx, const float* __restrict__ gnw,
                           float* __restrict__ y){
    __shared__ float red[256];
    int m = blockIdx.x, tid = threadIdx.x;
    size_t yb = (size_t)m*DIN, zb = (size_t)m*DIP;
    float g0 = y[yb+tid]     * siluf_(zx[zb+tid]);
    float g1 = y[yb+256+tid] * siluf_(zx[zb+256+tid]);
    red[tid] = g0*g0+g1*g1; __syncthreads();
    for(int o=128;o>0;o>>=1){ if(tid<o) red[tid]+=red[tid+o]; __syncthreads(); }
    float rstd = rsqrtf(red[0]*(1.f/512.f)+1e-5f);
    y[yb+tid]     = g0*rstd*gnw[tid];
    y[yb+256+tid] = g1*rstd*gnw[256+tid];
}

__global__ void k_mlp2(const float* __restrict__ h, const float* __restrict__ W2,
                       const float* __restrict__ b2, float* __restrict__ out){
    __shared__ float red[256];
    int m=blockIdx.x, tid=threadIdx.x;
    float hv=h[(size_t)m*Emb+tid];
    for(int j=0;j<5;j++){
        red[tid]=hv*W2[tid*5+j];
        __syncthreads();
        for(int o=128;o>0;o>>=1){ if(tid<o) red[tid]+=red[tid+o]; __syncthreads(); }
        if(tid==0) out[(size_t)m*5+j]=red[0]+b2[j];
        __syncthreads();
    }
}

extern "C" void kernel_launch(void* const* d_in, const int* in_sizes, int n_in,
                              void* d_out, int out_size, void* d_ws, size_t ws_size,
                              hipStream_t stream){
    const float* feature  = (const float*)d_in[0];
    const float* w_avg    = (const float*)d_in[1];
    const float* ipg      = (const float*)d_in[2];
    const float* ipb      = (const float*)d_in[3];
    const float* ipW      = (const float*)d_in[4];
    const float* ipbias   = (const float*)d_in[5];
    const float* rms_w    = (const float*)d_in[6];
    const float* m_inW    = (const float*)d_in[7];
    const float* m_convW  = (const float*)d_in[8];
    const float* m_convB  = (const float*)d_in[9];
    const float* m_dtb    = (const float*)d_in[10];
    const float* m_Alog   = (const float*)d_in[11];
    const float* m_D      = (const float*)d_in[12];
    const float* m_gnw    = (const float*)d_in[13];
    const float* m_outW   = (const float*)d_in[14];
    const float* norm_w   = (const float*)d_in[15];
    const float* mlp_ln_g = (const float*)d_in[16];
    const float* mlp_ln_b = (const float*)d_in[17];
    const float* W1       = (const float*)d_in[18];
    const float* b1       = (const float*)d_in[19];
    const float* W2       = (const float*)d_in[20];
    const float* b2       = (const float*)d_in[21];
    float* out = (float*)d_out;

    float* ws = (float*)d_ws;
    float* wsoft = ws;                                   // 16
    float* xin   = ws + 16;                              // M*128  (reused as S inside layers)
    float* xbuf  = xin  + (size_t)M_ROWS*Din;            // M*256
    float* ubuf  = xbuf + (size_t)M_ROWS*Emb;            // M*256
    float* zx    = ubuf + (size_t)M_ROWS*Emb;            // M*1160
    float* xc    = zx   + (size_t)M_ROWS*DIP;            // M*640
    float* dtb2  = xc   + (size_t)M_ROWS*CDIM;           // M*8
    float* dab   = dtb2 + (size_t)M_ROWS*NH;             // M*8
    float* ybuf  = dab  + (size_t)M_ROWS*NH;             // M*512
    float* Hbuf  = ybuf + (size_t)M_ROWS*DIN;            // Bsz*NH*NCHUNK*HD*DST = 2,097,152
    float* Pbuf  = Hbuf + (size_t)Bsz*NH*NCHUNK*HD*DST;  // 512
    float* Sbuf  = xin;                                  // exactly M*Din floats

    k_softmax_w<<<1,64,0,stream>>>(w_avg, wsoft);
    k_featsum<<<(M_ROWS*Din)/256,256,0,stream>>>(feature, wsoft, xin);
    k_layernorm<<<M_ROWS,256,0,stream>>>(xin, ipg, ipb, xin, Din);
    k_gemm<<<dim3(Emb/64, M_ROWS/64),256,0,stream>>>(xin, ipW, ipbias, xbuf, M_ROWS, Emb, Din, 0, 0);

    for(int i=0;i<NLAYERS;i++){
        k_rmsnorm<<<M_ROWS,256,0,stream>>>(xbuf, rms_w + i*Emb, ubuf, Emb);
        k_gemm<<<dim3((DIP+63)/64, M_ROWS/64),256,0,stream>>>(ubuf, m_inW + (size_t)i*Emb*DIP, nullptr, zx, M_ROWS, DIP, Emb, 0, 0);
        k_dt<<<(M_ROWS*NH)/256,256,0,stream>>>(zx, m_dtb + i*NH, m_Alog + i*NH, dtb2, dab);
        k_conv<<<(M_ROWS*CDIM)/256,256,0,stream>>>(zx, m_convW + (size_t)i*CDIM*DCONV, m_convB + i*CDIM, xc);
        k_scan1<<<Bsz*NH*4*NCHUNK,256,0,stream>>>(xc, dtb2, dab, Sbuf, Pbuf);
        k_scan2<<<Bsz*NH*4,256,0,stream>>>(Sbuf, Pbuf, Hbuf);
        k_scan3<<<Bsz*NH*4*NCHUNK,256,0,stream>>>(xc, dtb2, dab, Hbuf, m_D + i*NH, ybuf);
        k_gatenorm<<<M_ROWS,256,0,stream>>>(zx, m_gnw + i*DIN, ybuf);
        k_gemm<<<dim3(Emb/64, M_ROWS/64),256,0,stream>>>(ybuf, m_outW + (size_t)i*DIN*Emb, nullptr, xbuf, M_ROWS, Emb, DIN, 1, 0);
    }

    k_rmsnorm<<<M_ROWS,256,0,stream>>>(xbuf, norm_w, ubuf, Emb);
    k_layernorm<<<M_ROWS,256,0,stream>>>(ubuf, mlp_ln_g, mlp_ln_b, zx, Emb);
    k_gemm<<<dim3(Emb/64, M_ROWS/64),256,0,stream>>>(zx, W1, b1, ubuf, M_ROWS, Emb, Emb, 0, 1);
    k_mlp2<<<M_ROWS,256,0,stream>>>(ubuf, W2, b2, out);
}

// Round 4
// 1694.669 us; speedup vs baseline: 2.1562x; 1.3356x over previous
//
#include <hip/hip_runtime.h>
#include <math.h>

#define NLAYERS 3
#define NH 8
#define HD 64
#define DST 64
#define DCONV 4
#define DIN 512
#define Bsz 8
#define SEQ 2048
#define Din 128
#define Emb 256
#define DIP 1160
#define CDIM 640
#define M_ROWS (Bsz*SEQ)
#define NCHUNK 8
#define LCH (SEQ/NCHUNK)

typedef __attribute__((ext_vector_type(8))) short short8x;
typedef __attribute__((ext_vector_type(4))) float f32x4;
typedef unsigned short ushort_t;

__device__ __forceinline__ float sigmoidf_(float x){ return 1.f/(1.f+expf(-x)); }
__device__ __forceinline__ float siluf_(float x){ return x*sigmoidf_(x); }
__device__ __forceinline__ ushort_t f2bf(float f){
    unsigned x = __float_as_uint(f);
    unsigned r = (x + 0x7fffu + ((x>>16)&1u)) >> 16;
    return (ushort_t)r;
}
__device__ __forceinline__ float bf2f(ushort_t u){
    return __uint_as_float(((unsigned)u)<<16);
}

__global__ void k_softmax_w(const float* __restrict__ w_avg, float* __restrict__ w){
    if(threadIdx.x==0){
        float mx=-1e30f;
        for(int i=0;i<15;i++) mx=fmaxf(mx,w_avg[i]);
        float s=0.f,e[15];
        for(int i=0;i<15;i++){ e[i]=expf(w_avg[i]-mx); s+=e[i]; }
        for(int i=0;i<15;i++) w[i]=e[i]/s;
    }
}

__global__ void k_featsum(const float* __restrict__ feat, const float* __restrict__ w,
                          float* __restrict__ xin){
    int i = blockIdx.x*256+threadIdx.x;
    if(i < M_ROWS*Din){
        float acc=0.f;
        #pragma unroll
        for(int n=0;n<15;n++) acc += feat[(size_t)n*M_ROWS*Din + i]*w[n];
        xin[i]=acc;
    }
}

// weight convert+transpose: Wt[n][k] = bf16(W[k][n]), zero-pad n in [N,Npad)
__global__ void k_convw(const float* __restrict__ W, ushort_t* __restrict__ Wt,
                        int K, int N, int Npad){
    int idx = blockIdx.x*256+threadIdx.x;
    if(idx >= Npad*K) return;
    int n = idx / K, k = idx - n*K;
    float v = (n<N)? W[(size_t)k*N + n] : 0.f;
    Wt[idx] = f2bf(v);
}

__global__ void k_layernorm_bf(const float* __restrict__ in, const float* __restrict__ g,
                               const float* __restrict__ b, ushort_t* __restrict__ out, int D){
    __shared__ float buf[512];
    __shared__ float red[256];
    int m = blockIdx.x, tid = threadIdx.x;
    float s=0.f;
    for(int i=tid;i<D;i+=256){ float v=in[(size_t)m*D+i]; buf[i]=v; s+=v; }
    red[tid]=s; __syncthreads();
    for(int o=128;o>0;o>>=1){ if(tid<o) red[tid]+=red[tid+o]; __syncthreads(); }
    float mean = red[0]/(float)D; __syncthreads();
    float s2=0.f;
    for(int i=tid;i<D;i+=256){ float d=buf[i]-mean; s2+=d*d; }
    red[tid]=s2; __syncthreads();
    for(int o=128;o>0;o>>=1){ if(tid<o) red[tid]+=red[tid+o]; __syncthreads(); }
    float rstd = rsqrtf(red[0]/(float)D + 1e-5f);
    for(int i=tid;i<D;i+=256) out[(size_t)m*D+i] = f2bf((buf[i]-mean)*rstd*g[i]+b[i]);
}

__global__ void k_rmsnorm_bf(const float* __restrict__ in, const float* __restrict__ w,
                             ushort_t* __restrict__ out, int D){
    __shared__ float red[256];
    int m=blockIdx.x, tid=threadIdx.x;
    float s=0.f;
    for(int i=tid;i<D;i+=256){ float v=in[(size_t)m*D+i]; s+=v*v; }
    red[tid]=s; __syncthreads();
    for(int o=128;o>0;o>>=1){ if(tid<o) red[tid]+=red[tid+o]; __syncthreads(); }
    float rstd=rsqrtf(red[0]/(float)D+1e-5f);
    for(int i=tid;i<D;i+=256) out[(size_t)m*D+i]=f2bf(in[(size_t)m*D+i]*rstd*w[i]);
}

__global__ void k_rmsnorm_f(const float* __restrict__ in, const float* __restrict__ w,
                            float* __restrict__ out, int D){
    __shared__ float red[256];
    int m=blockIdx.x, tid=threadIdx.x;
    float s=0.f;
    for(int i=tid;i<D;i+=256){ float v=in[(size_t)m*D+i]; s+=v*v; }
    red[tid]=s; __syncthreads();
    for(int o=128;o>0;o>>=1){ if(tid<o) red[tid]+=red[tid+o]; __syncthreads(); }
    float rstd=rsqrtf(red[0]/(float)D+1e-5f);
    for(int i=tid;i<D;i+=256) out[(size_t)m*D+i]=in[(size_t)m*D+i]*rstd*w[i];
}

// bf16 MFMA GEMM: C[M,N](f32) = A[M,K](bf16) @ Bt[n][k](bf16, transposed, Npad rows)
// 128x128 tile, BK=64, 256 thr (4 waves, 2x2 of 64x64), 16x16x32 MFMA.
// LDS granule XOR swizzle g^(r&7) on both write and read.
__global__ void __launch_bounds__(256) k_gemm_bf16(
    const ushort_t* __restrict__ A, const ushort_t* __restrict__ Bt,
    const float* __restrict__ bias, float* __restrict__ C,
    int M, int N, int K, int accum, int act)
{
    __shared__ ushort_t As[128*64];
    __shared__ ushort_t Bs[128*64];
    int tid = threadIdx.x;
    int lane = tid & 63;
    int wave = tid >> 6;
    int l15 = lane & 15, l4 = lane >> 4;
    int wm = (wave>>1)*64, wn = (wave&1)*64;
    int n0 = blockIdx.x*128, m0 = blockIdx.y*128;
    f32x4 acc[4][4];
    #pragma unroll
    for(int i=0;i<4;i++)
        #pragma unroll
        for(int j=0;j<4;j++)
            acc[i][j] = (f32x4){0.f,0.f,0.f,0.f};

    for(int k0=0;k0<K;k0+=64){
        __syncthreads();
        #pragma unroll
        for(int i=0;i<4;i++){
            int slot = i*256 + tid;       // 0..1023  (r=slot/8 in 0..127, g=slot%8)
            int r = slot>>3, g = slot&7;
            int gs = g ^ (r&7);
            short8x va = *(const short8x*)(A  + (size_t)(m0+r)*K + k0 + g*8);
            *(short8x*)&As[(r*8+gs)*8] = va;
            short8x vb = *(const short8x*)(Bt + (size_t)(n0+r)*K + k0 + g*8);
            *(short8x*)&Bs[(r*8+gs)*8] = vb;
        }
        __syncthreads();
        #pragma unroll
        for(int kk=0;kk<2;kk++){
            short8x a[4], b[4];
            #pragma unroll
            for(int mf=0;mf<4;mf++){
                int r = wm + mf*16 + l15;
                int g = kk*4 + l4;
                a[mf] = *(const short8x*)&As[(r*8 + (g^(r&7)))*8];
            }
            #pragma unroll
            for(int nf=0;nf<4;nf++){
                int r = wn + nf*16 + l15;
                int g = kk*4 + l4;
                b[nf] = *(const short8x*)&Bs[(r*8 + (g^(r&7)))*8];
            }
            #pragma unroll
            for(int mf=0;mf<4;mf++)
                #pragma unroll
                for(int nf=0;nf<4;nf++)
                    acc[mf][nf] = __builtin_amdgcn_mfma_f32_16x16x32_bf16(a[mf], b[nf], acc[mf][nf], 0,0,0);
        }
    }

    #pragma unroll
    for(int mf=0;mf<4;mf++){
        #pragma unroll
        for(int nf=0;nf<4;nf++){
            int n = n0 + wn + nf*16 + l15;
            if(n < N){
                float bv = bias ? bias[n] : 0.f;
                int mb = m0 + wm + mf*16 + l4*4;
                #pragma unroll
                for(int j=0;j<4;j++){
                    float v = acc[mf][nf][j] + bv;
                    if(act) v = 0.5f*v*(1.f+erff(v*0.70710678118f));
                    size_t o = (size_t)(mb+j)*N + n;
                    if(accum) C[o] += v; else C[o] = v;
                }
            }
        }
    }
}

__global__ void k_dt(const float* __restrict__ zx, const float* __restrict__ dtbias,
                     const float* __restrict__ Alog, float* __restrict__ dt, float* __restrict__ da){
    int i = blockIdx.x*256+threadIdx.x;
    if(i<M_ROWS*NH){
        int m=i>>3, h=i&7;
        float v = zx[(size_t)m*DIP + (DIP-NH) + h] + dtbias[h];
        float d = (v>20.f)? v : log1pf(expf(v));
        dt[i]=d;
        da[i]=expf(-expf(Alog[h])*d);
    }
}

__global__ void k_conv(const float* __restrict__ zx, const float* __restrict__ cw,
                       const float* __restrict__ cb, float* __restrict__ xc){
    int i = blockIdx.x*256+threadIdx.x;
    if(i >= M_ROWS*CDIM) return;
    int c = i % CDIM; int m = i / CDIM; int s = m % SEQ;
    float acc = cb[c];
    #pragma unroll
    for(int k=0;k<4;k++){
        int t = s+k-3;
        if(t>=0) acc += zx[(size_t)(m+(t-s))*DIP + DIN + c] * cw[c*4+k];
    }
    xc[i] = siluf_(acc);
}

__global__ void __launch_bounds__(256) k_scan1(const float* __restrict__ xc, const float* __restrict__ dt,
                       const float* __restrict__ da, float* __restrict__ S, float* __restrict__ P){
    int blk = blockIdx.x;
    int c  = blk & (NCHUNK-1);
    int pc = (blk>>3) & 3;
    int h  = (blk>>5) & 7;
    int b  = blk>>8;
    int tid = threadIdx.x;
    int pl = tid>>4, nq = tid&15;
    int p = pc*16+pl;
    const float* xcb = xc + (size_t)b*SEQ*CDIM;
    const float* dtp = dt + (size_t)b*SEQ*NH + h;
    const float* dap = da + (size_t)b*SEQ*NH + h;
    int xoff = h*HD+p, boff = DIN+nq*4;
    int t0 = c*LCH, t1 = t0+LCH;
    float hr[4]={0,0,0,0};
    float pr = 1.f;
    const float* row = xcb + (size_t)t0*CDIM;
    float xv = row[xoff];
    float4 Bv = *(const float4*)(row+boff);
    float dtv = dtp[(size_t)t0*NH], dav = dap[(size_t)t0*NH];
    for(int t=t0;t<t1;t++){
        float nxv=0.f, ndt=0.f, nda=0.f; float4 nB=make_float4(0,0,0,0);
        if(t+1<t1){
            const float* nr = xcb + (size_t)(t+1)*CDIM;
            nxv = nr[xoff]; nB = *(const float4*)(nr+boff);
            ndt = dtp[(size_t)(t+1)*NH]; nda = dap[(size_t)(t+1)*NH];
        }
        float coef = dtv*xv;
        hr[0]=hr[0]*dav+coef*Bv.x; hr[1]=hr[1]*dav+coef*Bv.y;
        hr[2]=hr[2]*dav+coef*Bv.z; hr[3]=hr[3]*dav+coef*Bv.w;
        pr *= dav;
        xv=nxv; Bv=nB; dtv=ndt; dav=nda;
    }
    size_t sbase = (((size_t)(b*NH+h)*NCHUNK + c)*HD + p)*(size_t)DST + nq*4;
    *(float4*)(S+sbase) = make_float4(hr[0],hr[1],hr[2],hr[3]);
    if(tid==0) P[(b*NH+h)*NCHUNK+c] = pr;
}

__global__ void __launch_bounds__(256) k_scan2(const float* __restrict__ S, const float* __restrict__ P,
                       float* __restrict__ H){
    int blk = blockIdx.x;
    int pc = blk & 3, h = (blk>>2)&7, b = blk>>5;
    int tid = threadIdx.x;
    int pl = tid>>4, nq = tid&15;
    int p = pc*16+pl;
    size_t base = (((size_t)(b*NH+h)*NCHUNK)*HD + p)*(size_t)DST + nq*4;
    int pb = (b*NH+h)*NCHUNK;
    float4 run = make_float4(0,0,0,0);
    for(int c=0;c<NCHUNK;c++){
        size_t off = base + (size_t)c*HD*DST;
        *(float4*)(H+off) = run;
        float4 s = *(const float4*)(S+off);
        float pp = P[pb+c];
        run.x = run.x*pp + s.x; run.y = run.y*pp + s.y;
        run.z = run.z*pp + s.z; run.w = run.w*pp + s.w;
    }
}

__global__ void __launch_bounds__(256) k_scan3(const float* __restrict__ xc, const float* __restrict__ dt,
                       const float* __restrict__ da, const float* __restrict__ H,
                       const float* __restrict__ Dp, float* __restrict__ y){
    int blk = blockIdx.x;
    int c  = blk & (NCHUNK-1);
    int pc = (blk>>3) & 3;
    int h  = (blk>>5) & 7;
    int b  = blk>>8;
    int tid = threadIdx.x;
    int pl = tid>>4, nq = tid&15;
    int p = pc*16+pl;
    const float* xcb = xc + (size_t)b*SEQ*CDIM;
    const float* dtp = dt + (size_t)b*SEQ*NH + h;
    const float* dap = da + (size_t)b*SEQ*NH + h;
    float* yb = y + (size_t)b*SEQ*DIN + h*HD + p;
    float Dv = Dp[h];
    int xoff = h*HD+p, boff = DIN+nq*4, coff = DIN+DST+nq*4;
    int t0 = c*LCH, t1 = t0+LCH;
    size_t hbase = (((size_t)(b*NH+h)*NCHUNK + c)*HD + p)*(size_t)DST + nq*4;
    float4 h0 = *(const float4*)(H+hbase);
    float hr[4] = {h0.x,h0.y,h0.z,h0.w};
    const float* row = xcb + (size_t)t0*CDIM;
    float xv = row[xoff];
    float4 Bv = *(const float4*)(row+boff);
    float4 Cv = *(const float4*)(row+coff);
    float dtv = dtp[(size_t)t0*NH], dav = dap[(size_t)t0*NH];
    for(int t=t0;t<t1;t++){
        float nxv=0.f, ndt=0.f, nda=0.f; float4 nB=make_float4(0,0,0,0), nC=make_float4(0,0,0,0);
        if(t+1<t1){
            const float* nr = xcb + (size_t)(t+1)*CDIM;
            nxv = nr[xoff];
            nB = *(const float4*)(nr+boff);
            nC = *(const float4*)(nr+coff);
            ndt = dtp[(size_t)(t+1)*NH];
            nda = dap[(size_t)(t+1)*NH];
        }
        float coef = dtv*xv;
        hr[0]=hr[0]*dav+coef*Bv.x; hr[1]=hr[1]*dav+coef*Bv.y;
        hr[2]=hr[2]*dav+coef*Bv.z; hr[3]=hr[3]*dav+coef*Bv.w;
        float part = hr[0]*Cv.x + hr[1]*Cv.y + hr[2]*Cv.z + hr[3]*Cv.w;
        part += __shfl_xor(part,1,16);
        part += __shfl_xor(part,2,16);
        part += __shfl_xor(part,4,16);
        part += __shfl_xor(part,8,16);
        if(nq==0) yb[(size_t)t*DIN] = part + xv*Dv;
        xv=nxv; Bv=nB; Cv=nC; dtv=ndt; dav=nda;
    }
}

__global__ void k_gatenorm_bf(const float* __restrict__ zx, const float* __restrict__ gnw,
                              const float* __restrict__ y, ushort_t* __restrict__ out){
    __shared__ float red[256];
    int m = blockIdx.x, tid = threadIdx.x;
    size_t yb = (size_t)m*DIN, zb = (size_t)m*DIP;
    float g0 = y[yb+tid]     * siluf_(zx[zb+tid]);
    float g1 = y[yb+256+tid] * siluf_(zx[zb+256+tid]);
    red[tid] = g0*g0+g1*g1; __syncthreads();
    for(int o=128;o>0;o>>=1){ if(tid<o) red[tid]+=red[tid+o]; __syncthreads(); }
    float rstd = rsqrtf(red[0]*(1.f/512.f)+1e-5f);
    out[yb+tid]     = f2bf(g0*rstd*gnw[tid]);
    out[yb+256+tid] = f2bf(g1*rstd*gnw[256+tid]);
}

__global__ void k_mlp2(const float* __restrict__ h, const float* __restrict__ W2,
                       const float* __restrict__ b2, float* __restrict__ out){
    __shared__ float red[256];
    int m=blockIdx.x, tid=threadIdx.x;
    float hv=h[(size_t)m*Emb+tid];
    for(int j=0;j<5;j++){
        red[tid]=hv*W2[tid*5+j];
        __syncthreads();
        for(int o=128;o>0;o>>=1){ if(tid<o) red[tid]+=red[tid+o]; __syncthreads(); }
        if(tid==0) out[(size_t)m*5+j]=red[0]+b2[j];
        __syncthreads();
    }
}

extern "C" void kernel_launch(void* const* d_in, const int* in_sizes, int n_in,
                              void* d_out, int out_size, void* d_ws, size_t ws_size,
                              hipStream_t stream){
    const float* feature  = (const float*)d_in[0];
    const float* w_avg    = (const float*)d_in[1];
    const float* ipg      = (const float*)d_in[2];
    const float* ipb      = (const float*)d_in[3];
    const float* ipW      = (const float*)d_in[4];
    const float* ipbias   = (const float*)d_in[5];
    const float* rms_w    = (const float*)d_in[6];
    const float* m_inW    = (const float*)d_in[7];
    const float* m_convW  = (const float*)d_in[8];
    const float* m_convB  = (const float*)d_in[9];
    const float* m_dtb    = (const float*)d_in[10];
    const float* m_Alog   = (const float*)d_in[11];
    const float* m_D      = (const float*)d_in[12];
    const float* m_gnw    = (const float*)d_in[13];
    const float* m_outW   = (const float*)d_in[14];
    const float* norm_w   = (const float*)d_in[15];
    const float* mlp_ln_g = (const float*)d_in[16];
    const float* mlp_ln_b = (const float*)d_in[17];
    const float* W1       = (const float*)d_in[18];
    const float* b1       = (const float*)d_in[19];
    const float* W2       = (const float*)d_in[20];
    const float* b2       = (const float*)d_in[21];
    float* out = (float*)d_out;

    float* ws = (float*)d_ws;
    float* wsoft = ws;                                   // 16
    float* xin   = ws + 16;                              // M*128 f32 (featsum; reused as Sbuf)
    float* xbuf  = xin  + (size_t)M_ROWS*Din;            // M*256 (residual)
    float* zx    = xbuf + (size_t)M_ROWS*Emb;            // M*1160
    float* xc    = zx   + (size_t)M_ROWS*DIP;            // M*640
    float* dtb2  = xc   + (size_t)M_ROWS*CDIM;           // M*8
    float* dab   = dtb2 + (size_t)M_ROWS*NH;             // M*8
    float* ybuf  = dab  + (size_t)M_ROWS*NH;             // M*512
    float* abf_f = ybuf + (size_t)M_ROWS*DIN;            // M*256 words = M*512 bf16 (Abf)
    ushort_t* Abf = (ushort_t*)abf_f;
    float* Hbuf  = abf_f;                                // aliased: dead when Abf live & vice versa
    float* Pbuf  = Hbuf + (size_t)Bsz*NH*NCHUNK*HD*DST;  // still inside Abf region
    ushort_t* ipWt  = (ushort_t*)(abf_f + (size_t)M_ROWS*Emb);  // 256*128
    ushort_t* inWt  = ipWt + 256*128;                    // 3 * 1280*256
    ushort_t* outWt = inWt + (size_t)3*1280*256;         // 3 * 256*512
    ushort_t* W1t   = outWt + (size_t)3*256*512;         // 256*256
    float* Sbuf  = xin;

    // one-time (per launch) weight convert+transpose
    k_convw<<<(256*128+255)/256,256,0,stream>>>(ipW, ipWt, 128, 256, 256);
    for(int i=0;i<NLAYERS;i++){
        k_convw<<<(1280*256+255)/256,256,0,stream>>>(m_inW + (size_t)i*Emb*DIP, inWt + (size_t)i*1280*256, 256, 1160, 1280);
        k_convw<<<(256*512+255)/256,256,0,stream>>>(m_outW + (size_t)i*DIN*Emb, outWt + (size_t)i*256*512, 512, 256, 256);
    }
    k_convw<<<(256*256+255)/256,256,0,stream>>>(W1, W1t, 256, 256, 256);

    k_softmax_w<<<1,64,0,stream>>>(w_avg, wsoft);
    k_featsum<<<(M_ROWS*Din)/256,256,0,stream>>>(feature, wsoft, xin);
    k_layernorm_bf<<<M_ROWS,256,0,stream>>>(xin, ipg, ipb, Abf, Din);
    k_gemm_bf16<<<dim3(2, M_ROWS/128),256,0,stream>>>(Abf, ipWt, ipbias, xbuf, M_ROWS, Emb, Din, 0, 0);

    for(int i=0;i<NLAYERS;i++){
        k_rmsnorm_bf<<<M_ROWS,256,0,stream>>>(xbuf, rms_w + i*Emb, Abf, Emb);
        k_gemm_bf16<<<dim3(10, M_ROWS/128),256,0,stream>>>(Abf, inWt + (size_t)i*1280*256, nullptr, zx, M_ROWS, DIP, Emb, 0, 0);
        k_dt<<<(M_ROWS*NH)/256,256,0,stream>>>(zx, m_dtb + i*NH, m_Alog + i*NH, dtb2, dab);
        k_conv<<<(M_ROWS*CDIM)/256,256,0,stream>>>(zx, m_convW + (size_t)i*CDIM*DCONV, m_convB + i*CDIM, xc);
        k_scan1<<<Bsz*NH*4*NCHUNK,256,0,stream>>>(xc, dtb2, dab, Sbuf, Pbuf);
        k_scan2<<<Bsz*NH*4,256,0,stream>>>(Sbuf, Pbuf, Hbuf);
        k_scan3<<<Bsz*NH*4*NCHUNK,256,0,stream>>>(xc, dtb2, dab, Hbuf, m_D + i*NH, ybuf);
        k_gatenorm_bf<<<M_ROWS,256,0,stream>>>(zx, m_gnw + i*DIN, ybuf, Abf);
        k_gemm_bf16<<<dim3(2, M_ROWS/128),256,0,stream>>>(Abf, outWt + (size_t)i*256*512, nullptr, xbuf, M_ROWS, Emb, DIN, 1, 0);
    }

    k_rmsnorm_f<<<M_ROWS,256,0,stream>>>(xbuf, norm_w, xc, Emb);
    k_layernorm_bf<<<M_ROWS,256,0,stream>>>(xc, mlp_ln_g, mlp_ln_b, Abf, Emb);
    k_gemm_bf16<<<dim3(2, M_ROWS/128),256,0,stream>>>(Abf, W1t, b1, zx, M_ROWS, Emb, Emb, 0, 1);
    k_mlp2<<<M_ROWS,256,0,stream>>>(zx, W2, b2, out);
}

// Round 6
// 1014.128 us; speedup vs baseline: 3.6032x; 1.6711x over previous
//
#include <hip/hip_runtime.h>
#include <math.h>

#define NLAYERS 3
#define NH 8
#define HD 64
#define DST 64
#define DCONV 4
#define DIN 512
#define Bsz 8
#define SEQ 2048
#define Din 128
#define Emb 256
#define DIP 1160
#define CDIM 640
#define M_ROWS (Bsz*SEQ)
#define NCH 32
#define CL 64

typedef __attribute__((ext_vector_type(8))) short short8x;
typedef __attribute__((ext_vector_type(4))) float f32x4;
typedef unsigned short ushort_t;

__device__ __forceinline__ float sigmoidf_(float x){ return 1.f/(1.f+expf(-x)); }
__device__ __forceinline__ float siluf_(float x){ return x*sigmoidf_(x); }
__device__ __forceinline__ ushort_t f2bf(float f){
    unsigned x = __float_as_uint(f);
    unsigned r = (x + 0x7fffu + ((x>>16)&1u)) >> 16;
    return (ushort_t)r;
}

// swizzled LDS layout: [row][64] bf16, granule(8 bf16) g stored at g^(row&7)
#define FRAG(buf, r, kg) (*(const short8x*)&buf[((((r)<<3) + ((kg)^((r)&7)))<<3)])
#define EIDX(r, k) (((((r)<<3) + ((((k)>>3))^((r)&7)))<<3) | ((k)&7))

__device__ __forceinline__ void pack_store8(ushort_t* dst, const float* v){
    short8x s;
    #pragma unroll
    for(int e=0;e<8;e++) ((ushort_t*)&s)[e]=f2bf(v[e]);
    *(short8x*)dst = s;
}

__global__ void k_softmax_w(const float* __restrict__ w_avg, float* __restrict__ w){
    if(threadIdx.x==0){
        float mx=-1e30f;
        for(int i=0;i<15;i++) mx=fmaxf(mx,w_avg[i]);
        float s=0.f,e[15];
        for(int i=0;i<15;i++){ e[i]=expf(w_avg[i]-mx); s+=e[i]; }
        for(int i=0;i<15;i++) w[i]=e[i]/s;
    }
}

__global__ void k_featsum(const float* __restrict__ feat, const float* __restrict__ w,
                          float* __restrict__ xin){
    int i = blockIdx.x*256+threadIdx.x;
    if(i < M_ROWS*Din){
        float acc=0.f;
        #pragma unroll
        for(int n=0;n<15;n++) acc += feat[(size_t)n*M_ROWS*Din + i]*w[n];
        xin[i]=acc;
    }
}

__global__ void k_convw(const float* __restrict__ W, ushort_t* __restrict__ Wt,
                        int K, int N, int Npad){
    int idx = blockIdx.x*256+threadIdx.x;
    if(idx >= Npad*K) return;
    int n = idx / K, k = idx - n*K;
    float v = (n<N)? W[(size_t)k*N + n] : 0.f;
    Wt[idx] = f2bf(v);
}

__global__ void k_layernorm_bf(const float* __restrict__ in, const float* __restrict__ g,
                               const float* __restrict__ b, ushort_t* __restrict__ out, int D){
    __shared__ float buf[512];
    __shared__ float red[256];
    int m = blockIdx.x, tid = threadIdx.x;
    float s=0.f;
    for(int i=tid;i<D;i+=256){ float v=in[(size_t)m*D+i]; buf[i]=v; s+=v; }
    red[tid]=s; __syncthreads();
    for(int o=128;o>0;o>>=1){ if(tid<o) red[tid]+=red[tid+o]; __syncthreads(); }
    float mean = red[0]/(float)D; __syncthreads();
    float s2=0.f;
    for(int i=tid;i<D;i+=256){ float d=buf[i]-mean; s2+=d*d; }
    red[tid]=s2; __syncthreads();
    for(int o=128;o>0;o>>=1){ if(tid<o) red[tid]+=red[tid+o]; __syncthreads(); }
    float rstd = rsqrtf(red[0]/(float)D + 1e-5f);
    for(int i=tid;i<D;i+=256) out[(size_t)m*D+i] = f2bf((buf[i]-mean)*rstd*g[i]+b[i]);
}

__global__ void k_rmsnorm_bf(const float* __restrict__ in, const float* __restrict__ w,
                             ushort_t* __restrict__ out, int D){
    __shared__ float red[256];
    int m=blockIdx.x, tid=threadIdx.x;
    float s=0.f;
    for(int i=tid;i<D;i+=256){ float v=in[(size_t)m*D+i]; s+=v*v; }
    red[tid]=s; __syncthreads();
    for(int o=128;o>0;o>>=1){ if(tid<o) red[tid]+=red[tid+o]; __syncthreads(); }
    float rstd=rsqrtf(red[0]/(float)D+1e-5f);
    for(int i=tid;i<D;i+=256) out[(size_t)m*D+i]=f2bf(in[(size_t)m*D+i]*rstd*w[i]);
}

__global__ void k_rmsnorm_f(const float* __restrict__ in, const float* __restrict__ w,
                            float* __restrict__ out, int D){
    __shared__ float red[256];
    int m=blockIdx.x, tid=threadIdx.x;
    float s=0.f;
    for(int i=tid;i<D;i+=256){ float v=in[(size_t)m*D+i]; s+=v*v; }
    red[tid]=s; __syncthreads();
    for(int o=128;o>0;o>>=1){ if(tid<o) red[tid]+=red[tid+o]; __syncthreads(); }
    float rstd=rsqrtf(red[0]/(float)D+1e-5f);
    for(int i=tid;i<D;i+=256) out[(size_t)m*D+i]=in[(size_t)m*D+i]*rstd*w[i];
}

// bf16 MFMA GEMM
__global__ void __launch_bounds__(256) k_gemm_bf16(
    const ushort_t* __restrict__ A, const ushort_t* __restrict__ Bt,
    const float* __restrict__ bias, float* __restrict__ C,
    int M, int N, int K, int accum, int act)
{
    __shared__ ushort_t As[128*64];
    __shared__ ushort_t Bs[128*64];
    int tid = threadIdx.x;
    int lane = tid & 63;
    int wave = tid >> 6;
    int l15 = lane & 15, l4 = lane >> 4;
    int wm = (wave>>1)*64, wn = (wave&1)*64;
    int n0 = blockIdx.x*128, m0 = blockIdx.y*128;
    f32x4 acc[4][4];
    #pragma unroll
    for(int i=0;i<4;i++)
        #pragma unroll
        for(int j=0;j<4;j++)
            acc[i][j] = (f32x4){0.f,0.f,0.f,0.f};

    for(int k0=0;k0<K;k0+=64){
        __syncthreads();
        #pragma unroll
        for(int i=0;i<4;i++){
            int slot = i*256 + tid;
            int r = slot>>3, g = slot&7;
            int gs = g ^ (r&7);
            short8x va = *(const short8x*)(A  + (size_t)(m0+r)*K + k0 + g*8);
            *(short8x*)&As[(r*8+gs)*8] = va;
            short8x vb = *(const short8x*)(Bt + (size_t)(n0+r)*K + k0 + g*8);
            *(short8x*)&Bs[(r*8+gs)*8] = vb;
        }
        __syncthreads();
        #pragma unroll
        for(int kk=0;kk<2;kk++){
            short8x a[4], b[4];
            #pragma unroll
            for(int mf=0;mf<4;mf++) a[mf] = FRAG(As, wm+mf*16+l15, kk*4+l4);
            #pragma unroll
            for(int nf=0;nf<4;nf++) b[nf] = FRAG(Bs, wn+nf*16+l15, kk*4+l4);
            #pragma unroll
            for(int mf=0;mf<4;mf++)
                #pragma unroll
                for(int nf=0;nf<4;nf++)
                    acc[mf][nf] = __builtin_amdgcn_mfma_f32_16x16x32_bf16(a[mf], b[nf], acc[mf][nf], 0,0,0);
        }
    }

    #pragma unroll
    for(int mf=0;mf<4;mf++){
        #pragma unroll
        for(int nf=0;nf<4;nf++){
            int n = n0 + wn + nf*16 + l15;
            if(n < N){
                float bv = bias ? bias[n] : 0.f;
                int mb = m0 + wm + mf*16 + l4*4;
                #pragma unroll
                for(int j=0;j<4;j++){
                    float v = acc[mf][nf][j] + bv;
                    if(act) v = 0.5f*v*(1.f+erff(v*0.70710678118f));
                    size_t o = (size_t)(mb+j)*N + n;
                    if(accum) C[o] += v; else C[o] = v;
                }
            }
        }
    }
}

// dt = softplus(raw+bias); ldA = -exp(Alog)*dt  (log of decay)
__global__ void k_dt(const float* __restrict__ zx, const float* __restrict__ dtbias,
                     const float* __restrict__ Alog, float* __restrict__ dt, float* __restrict__ ldab){
    int i = blockIdx.x*256+threadIdx.x;
    if(i<M_ROWS*NH){
        int m=i>>3, h=i&7;
        float v = zx[(size_t)m*DIP + (DIP-NH) + h] + dtbias[h];
        float d = (v>20.f)? v : log1pf(expf(v));
        dt[i]=d;
        ldab[i]= -expf(Alog[h])*d;
    }
}

__global__ void k_conv(const float* __restrict__ zx, const float* __restrict__ cw,
                       const float* __restrict__ cb, float* __restrict__ xc){
    int i = blockIdx.x*256+threadIdx.x;
    if(i >= M_ROWS*CDIM) return;
    int c = i % CDIM; int m = i / CDIM; int s = m % SEQ;
    float acc = cb[c];
    #pragma unroll
    for(int k=0;k<4;k++){
        int t = s+k-3;
        if(t>=0) acc += zx[(size_t)(m+(t-s))*DIP + DIN + c] * cw[c*4+k];
    }
    xc[i] = siluf_(acc);
}

// SSD pass A: per (b,h,chunk) compute S_c[p][n] = sum_t exp(cum[63]-cum[t])*dt_t*x_t[p]*B_t[n]
__global__ void __launch_bounds__(256) k_chstate(
    const float* __restrict__ xc, const float* __restrict__ dt,
    const float* __restrict__ ldab, float* __restrict__ S, float* __restrict__ cumbuf)
{
    __shared__ ushort_t XwW[64*64];
    __shared__ ushort_t Bn[64*64];
    __shared__ float lda_s[64];
    __shared__ float cum_s[64];
    int blk = blockIdx.x;
    int c = blk & (NCH-1);
    int h = (blk>>5) & 7;
    int b = blk>>8;
    int tid = threadIdx.x;
    int bh = b*NH+h;
    size_t bt0 = (size_t)b*SEQ + c*CL;
    if(tid<64) lda_s[tid] = ldab[(bt0+tid)*NH + h];
    __syncthreads();
    if(tid==0){
        float r=0.f;
        for(int t=0;t<64;t++){ r += lda_s[t]; cum_s[t]=r; }
    }
    __syncthreads();
    {
        int t = tid>>2, q = tid&3;
        const float* row = xc + (bt0+t)*CDIM;
        float w = expf(cum_s[63]-cum_s[t]) * dt[(bt0+t)*NH + h];
        float xv[16], bv[16];
        #pragma unroll
        for(int i4=0;i4<4;i4++){
            *(float4*)&xv[i4*4] = *(const float4*)(row + h*HD + q*16 + i4*4);
            *(float4*)&bv[i4*4] = *(const float4*)(row + DIN  + q*16 + i4*4);
        }
        #pragma unroll
        for(int i=0;i<16;i++){
            int p = q*16+i;
            XwW[EIDX(p,t)] = f2bf(w*xv[i]);
            Bn [EIDX(p,t)] = f2bf(bv[i]);
        }
    }
    __syncthreads();
    int lane = tid&63, wave = tid>>6, l15=lane&15, l4=lane>>4;
    f32x4 sacc[4];
    #pragma unroll
    for(int nt=0;nt<4;nt++) sacc[nt]=(f32x4){0.f,0.f,0.f,0.f};
    #pragma unroll
    for(int kk=0;kk<2;kk++){
        short8x a = FRAG(XwW, wave*16+l15, kk*4+l4);
        #pragma unroll
        for(int nt=0;nt<4;nt++){
            short8x bb = FRAG(Bn, nt*16+l15, kk*4+l4);
            sacc[nt] = __builtin_amdgcn_mfma_f32_16x16x32_bf16(a, bb, sacc[nt], 0,0,0);
        }
    }
    size_t sb = ((size_t)bh*NCH + c)*4096;
    #pragma unroll
    for(int nt=0;nt<4;nt++)
        #pragma unroll
        for(int j=0;j<4;j++)
            S[sb + (size_t)(wave*16+l4*4+j)*64 + nt*16+l15] = sacc[nt][j];
    if(tid<64) cumbuf[((size_t)bh*NCH+c)*64 + tid] = cum_s[tid];
}

// SSD pass B: serial combine over 32 chunks per (b,h); emits H (state at chunk start) as bf16
__global__ void __launch_bounds__(256) k_comb(const float* __restrict__ S,
                      const float* __restrict__ cumbuf, ushort_t* __restrict__ Hg){
    int bh = blockIdx.x;
    int tid = threadIdx.x;
    float run[16];
    #pragma unroll
    for(int e=0;e<16;e++) run[e]=0.f;
    for(int c=0;c<NCH;c++){
        size_t base = ((size_t)bh*NCH + c)*4096 + tid*16;
        pack_store8(Hg+base, run);
        pack_store8(Hg+base+8, run+8);
        float P = expf(cumbuf[((size_t)bh*NCH+c)*64 + 63]);
        #pragma unroll
        for(int i4=0;i4<4;i4++){
            float4 s = *(const float4*)(S + base + i4*4);
            run[i4*4+0]=run[i4*4+0]*P + s.x;
            run[i4*4+1]=run[i4*4+1]*P + s.y;
            run[i4*4+2]=run[i4*4+2]*P + s.z;
            run[i4*4+3]=run[i4*4+3]*P + s.w;
        }
    }
}

// SSD pass C: y[t,p] = [L ∘ (C·B^T)] @ (dt·x)  +  exp(cum[t]) * C·H^T  +  D*x
__global__ void __launch_bounds__(256) k_chout(
    const float* __restrict__ xc, const float* __restrict__ dt,
    const ushort_t* __restrict__ Hg, const float* __restrict__ cumbuf,
    const float* __restrict__ Dp, float* __restrict__ y)
{
    __shared__ ushort_t Cs[64*64];
    __shared__ ushort_t Bm[64*64];
    __shared__ ushort_t Xw[64*64];
    __shared__ ushort_t Gs[64*64];
    __shared__ ushort_t Hs[64*64];
    __shared__ float cum_s[64];
    int blk = blockIdx.x;
    int c = blk & (NCH-1);
    int h = (blk>>5) & 7;
    int b = blk>>8;
    int tid = threadIdx.x;
    int bh = b*NH+h;
    size_t bt0 = (size_t)b*SEQ + c*CL;
    if(tid<64) cum_s[tid] = cumbuf[((size_t)bh*NCH+c)*64 + tid];
    {
        int t = tid>>2, q = tid&3;
        const float* row = xc + (bt0+t)*CDIM;
        float dtl = dt[(bt0+t)*NH + h];
        float xv[16], bv[16], cv[16];
        #pragma unroll
        for(int i4=0;i4<4;i4++){
            *(float4*)&xv[i4*4] = *(const float4*)(row + h*HD      + q*16 + i4*4);
            *(float4*)&bv[i4*4] = *(const float4*)(row + DIN       + q*16 + i4*4);
            *(float4*)&cv[i4*4] = *(const float4*)(row + DIN+DST   + q*16 + i4*4);
        }
        pack_store8(&Cs[EIDX(t, q*16)],   cv);
        pack_store8(&Cs[EIDX(t, q*16+8)], cv+8);
        pack_store8(&Bm[EIDX(t, q*16)],   bv);
        pack_store8(&Bm[EIDX(t, q*16+8)], bv+8);
        #pragma unroll
        for(int i=0;i<16;i++){
            int p = q*16+i;
            Xw[EIDX(p,t)] = f2bf(dtl*xv[i]);
        }
        const ushort_t* hr = Hg + ((size_t)bh*NCH+c)*4096 + (size_t)t*64 + q*16;
        *(short8x*)&Hs[EIDX(t, q*16)]   = *(const short8x*)hr;
        *(short8x*)&Hs[EIDX(t, q*16+8)] = *(const short8x*)(hr+8);
    }
    __syncthreads();
    int lane = tid&63, wave = tid>>6, l15=lane&15, l4=lane>>4;
    // phase 1: M = C·B^T
    f32x4 macc[4];
    #pragma unroll
    for(int st=0;st<4;st++) macc[st]=(f32x4){0.f,0.f,0.f,0.f};
    #pragma unroll
    for(int kk=0;kk<2;kk++){
        short8x a = FRAG(Cs, wave*16+l15, kk*4+l4);
        #pragma unroll
        for(int st=0;st<4;st++){
            short8x bb = FRAG(Bm, st*16+l15, kk*4+l4);
            macc[st] = __builtin_amdgcn_mfma_f32_16x16x32_bf16(a, bb, macc[st], 0,0,0);
        }
    }
    // mask + decay -> G (bf16, swizzled LDS)
    #pragma unroll
    for(int st=0;st<4;st++){
        #pragma unroll
        for(int j=0;j<4;j++){
            int t = wave*16 + l4*4 + j;
            int s = st*16 + l15;
            float g = (s<=t)? macc[st][j]*expf(cum_s[t]-cum_s[s]) : 0.f;
            Gs[EIDX(t,s)] = f2bf(g);
        }
    }
    __syncthreads();
    // phase 2: acc = C·H^T, scaled by exp(cum[t])
    f32x4 acc[4];
    #pragma unroll
    for(int pt=0;pt<4;pt++) acc[pt]=(f32x4){0.f,0.f,0.f,0.f};
    #pragma unroll
    for(int kk=0;kk<2;kk++){
        short8x a = FRAG(Cs, wave*16+l15, kk*4+l4);
        #pragma unroll
        for(int pt=0;pt<4;pt++){
            short8x bb = FRAG(Hs, pt*16+l15, kk*4+l4);
            acc[pt] = __builtin_amdgcn_mfma_f32_16x16x32_bf16(a, bb, acc[pt], 0,0,0);
        }
    }
    float ef[4];
    #pragma unroll
    for(int j=0;j<4;j++) ef[j] = expf(cum_s[wave*16 + l4*4 + j]);
    #pragma unroll
    for(int pt=0;pt<4;pt++)
        #pragma unroll
        for(int j=0;j<4;j++) acc[pt][j] *= ef[j];
    // phase 3: acc += G @ Xw
    #pragma unroll
    for(int kk=0;kk<2;kk++){
        short8x a = FRAG(Gs, wave*16+l15, kk*4+l4);
        #pragma unroll
        for(int pt=0;pt<4;pt++){
            short8x bb = FRAG(Xw, pt*16+l15, kk*4+l4);
            acc[pt] = __builtin_amdgcn_mfma_f32_16x16x32_bf16(a, bb, acc[pt], 0,0,0);
        }
    }
    // epilogue: + D*x, write y
    float Dv = Dp[h];
    #pragma unroll
    for(int pt=0;pt<4;pt++){
        #pragma unroll
        for(int j=0;j<4;j++){
            int t = wave*16 + l4*4 + j;
            int p = pt*16 + l15;
            size_t ro = bt0 + t;
            y[ro*DIN + h*HD + p] = acc[pt][j] + Dv*xc[ro*CDIM + h*HD + p];
        }
    }
}

__global__ void k_gatenorm_bf(const float* __restrict__ zx, const float* __restrict__ gnw,
                              const float* __restrict__ y, ushort_t* __restrict__ out){
    __shared__ float red[256];
    int m = blockIdx.x, tid = threadIdx.x;
    size_t yb = (size_t)m*DIN, zb = (size_t)m*DIP;
    float g0 = y[yb+tid]     * siluf_(zx[zb+tid]);
    float g1 = y[yb+256+tid] * siluf_(zx[zb+256+tid]);
    red[tid] = g0*g0+g1*g1; __syncthreads();
    for(int o=128;o>0;o>>=1){ if(tid<o) red[tid]+=red[tid+o]; __syncthreads(); }
    float rstd = rsqrtf(red[0]*(1.f/512.f)+1e-5f);
    out[yb+tid]     = f2bf(g0*rstd*gnw[tid]);
    out[yb+256+tid] = f2bf(g1*rstd*gnw[256+tid]);
}

__global__ void k_mlp2(const float* __restrict__ h, const float* __restrict__ W2,
                       const float* __restrict__ b2, float* __restrict__ out){
    __shared__ float red[256];
    int m=blockIdx.x, tid=threadIdx.x;
    float hv=h[(size_t)m*Emb+tid];
    for(int j=0;j<5;j++){
        red[tid]=hv*W2[tid*5+j];
        __syncthreads();
        for(int o=128;o>0;o>>=1){ if(tid<o) red[tid]+=red[tid+o]; __syncthreads(); }
        if(tid==0) out[(size_t)m*5+j]=red[0]+b2[j];
        __syncthreads();
    }
}

extern "C" void kernel_launch(void* const* d_in, const int* in_sizes, int n_in,
                              void* d_out, int out_size, void* d_ws, size_t ws_size,
                              hipStream_t stream){
    const float* feature  = (const float*)d_in[0];
    const float* w_avg    = (const float*)d_in[1];
    const float* ipg      = (const float*)d_in[2];
    const float* ipb      = (const float*)d_in[3];
    const float* ipW      = (const float*)d_in[4];
    const float* ipbias   = (const float*)d_in[5];
    const float* rms_w    = (const float*)d_in[6];
    const float* m_inW    = (const float*)d_in[7];
    const float* m_convW  = (const float*)d_in[8];
    const float* m_convB  = (const float*)d_in[9];
    const float* m_dtb    = (const float*)d_in[10];
    const float* m_Alog   = (const float*)d_in[11];
    const float* m_D      = (const float*)d_in[12];
    const float* m_gnw    = (const float*)d_in[13];
    const float* m_outW   = (const float*)d_in[14];
    const float* norm_w   = (const float*)d_in[15];
    const float* mlp_ln_g = (const float*)d_in[16];
    const float* mlp_ln_b = (const float*)d_in[17];
    const float* W1       = (const float*)d_in[18];
    const float* b1       = (const float*)d_in[19];
    const float* W2       = (const float*)d_in[20];
    const float* b2       = (const float*)d_in[21];
    float* out = (float*)d_out;

    float* ws = (float*)d_ws;
    float* wsoft = ws;                                   // 16
    float* xin   = ws + 16;                              // M*128
    float* xbuf  = xin  + (size_t)M_ROWS*Din;            // M*256 (residual)
    float* zx    = xbuf + (size_t)M_ROWS*Emb;            // M*1160
    float* xc    = zx   + (size_t)M_ROWS*DIP;            // M*640
    float* dtb2  = xc   + (size_t)M_ROWS*CDIM;           // M*8
    float* ldab  = dtb2 + (size_t)M_ROWS*NH;             // M*8
    float* ybuf  = ldab + (size_t)M_ROWS*NH;             // M*512  (alias: Sbuf)
    float* abf_f = ybuf + (size_t)M_ROWS*DIN;            // M*256 f32 = M*512 ushort (Abf / Hbf alias)
    ushort_t* Abf = (ushort_t*)abf_f;
    ushort_t* Hbf = Abf;                                 // alias (disjoint lifetime)
    float* Sbuf  = ybuf;                                 // alias (disjoint lifetime)
    ushort_t* ipWt  = (ushort_t*)(abf_f + (size_t)M_ROWS*Emb);  // 256*128
    ushort_t* inWt  = ipWt + 256*128;                    // 3 * 1280*256
    ushort_t* outWt = inWt + (size_t)3*1280*256;         // 3 * 256*512
    ushort_t* W1t   = outWt + (size_t)3*256*512;         // 256*256
    float* cumbuf = (float*)(W1t + 256*256);             // 64*32*64 = 131072

    k_convw<<<(256*128+255)/256,256,0,stream>>>(ipW, ipWt, 128, 256, 256);
    for(int i=0;i<NLAYERS;i++){
        k_convw<<<(1280*256+255)/256,256,0,stream>>>(m_inW + (size_t)i*Emb*DIP, inWt + (size_t)i*1280*256, 256, 1160, 1280);
        k_convw<<<(256*512+255)/256,256,0,stream>>>(m_outW + (size_t)i*DIN*Emb, outWt + (size_t)i*256*512, 512, 256, 256);
    }
    k_convw<<<(256*256+255)/256,256,0,stream>>>(W1, W1t, 256, 256, 256);

    k_softmax_w<<<1,64,0,stream>>>(w_avg, wsoft);
    k_featsum<<<(M_ROWS*Din)/256,256,0,stream>>>(feature, wsoft, xin);
    k_layernorm_bf<<<M_ROWS,256,0,stream>>>(xin, ipg, ipb, Abf, Din);
    k_gemm_bf16<<<dim3(2, M_ROWS/128),256,0,stream>>>(Abf, ipWt, ipbias, xbuf, M_ROWS, Emb, Din, 0, 0);

    for(int i=0;i<NLAYERS;i++){
        k_rmsnorm_bf<<<M_ROWS,256,0,stream>>>(xbuf, rms_w + i*Emb, Abf, Emb);
        k_gemm_bf16<<<dim3(10, M_ROWS/128),256,0,stream>>>(Abf, inWt + (size_t)i*1280*256, nullptr, zx, M_ROWS, DIP, Emb, 0, 0);
        k_dt<<<(M_ROWS*NH)/256,256,0,stream>>>(zx, m_dtb + i*NH, m_Alog + i*NH, dtb2, ldab);
        k_conv<<<(M_ROWS*CDIM)/256,256,0,stream>>>(zx, m_convW + (size_t)i*CDIM*DCONV, m_convB + i*CDIM, xc);
        k_chstate<<<Bsz*NH*NCH,256,0,stream>>>(xc, dtb2, ldab, Sbuf, cumbuf);
        k_comb<<<Bsz*NH,256,0,stream>>>(Sbuf, cumbuf, Hbf);
        k_chout<<<Bsz*NH*NCH,256,0,stream>>>(xc, dtb2, Hbf, cumbuf, m_D + i*NH, ybuf);
        k_gatenorm_bf<<<M_ROWS,256,0,stream>>>(zx, m_gnw + i*DIN, ybuf, Abf);
        k_gemm_bf16<<<dim3(2, M_ROWS/128),256,0,stream>>>(Abf, outWt + (size_t)i*256*512, nullptr, xbuf, M_ROWS, Emb, DIN, 1, 0);
    }

    k_rmsnorm_f<<<M_ROWS,256,0,stream>>>(xbuf, norm_w, xc, Emb);
    k_layernorm_bf<<<M_ROWS,256,0,stream>>>(xc, mlp_ln_g, mlp_ln_b, Abf, Emb);
    k_gemm_bf16<<<dim3(2, M_ROWS/128),256,0,stream>>>(Abf, W1t, b1, zx, M_ROWS, Emb, Emb, 0, 1);
    k_mlp2<<<M_ROWS,256,0,stream>>>(zx, W2, b2, out);
}